// Round 17
// baseline (136.207 us; speedup 1.0000x reference)
//
#include <hip/hip_runtime.h>
#include <stdint.h>

typedef __bf16 bf16;
typedef __bf16 bf16x8 __attribute__((ext_vector_type(8)));
typedef __bf16 bf16x4 __attribute__((ext_vector_type(4)));
typedef float f32x4 __attribute__((ext_vector_type(4)));

#define T_TOT 6144
#define E_DIM 1024
#define NHEAD 16

// async global->LDS, 16B per lane; LDS dest = wave-uniform base + lane*16
__device__ __forceinline__ void gload16(const void* g, void* l) {
    __builtin_amdgcn_global_load_lds((const __attribute__((address_space(1))) void*)g,
                                     (__attribute__((address_space(3))) void*)l, 16, 0, 0);
}

// ---------------- fused f32 -> bf16 conversion (all 5 buffers) ----------------
__global__ __launch_bounds__(256) void cvt_all_kernel(const float* __restrict__ hs,
        const float* __restrict__ wq, const float* __restrict__ wk,
        const float* __restrict__ wv, const float* __restrict__ wo,
        bf16* __restrict__ hsb, bf16* __restrict__ wqb, bf16* __restrict__ wkb,
        bf16* __restrict__ wvb, bf16* __restrict__ wob) {
    const size_t TE = (size_t)T_TOT * E_DIM;
    const size_t EE = (size_t)E_DIM * E_DIM;
    size_t i = ((size_t)blockIdx.x * 256 + threadIdx.x) * 4;
    const float* src; bf16* dst; size_t off;
    if (i < TE)               { src = hs; dst = hsb; off = i; }
    else if (i < TE + EE)     { src = wq; dst = wqb; off = i - TE; }
    else if (i < TE + 2 * EE) { src = wk; dst = wkb; off = i - TE - EE; }
    else if (i < TE + 3 * EE) { src = wv; dst = wvb; off = i - TE - 2 * EE; }
    else                      { src = wo; dst = wob; off = i - TE - 3 * EE; }
    float4 v = *reinterpret_cast<const float4*>(src + off);
    union { bf16 h[4]; uint2 u; } pk;
    pk.h[0] = (bf16)v.x; pk.h[1] = (bf16)v.y; pk.h[2] = (bf16)v.z; pk.h[3] = (bf16)v.w;
    *reinterpret_cast<uint2*>(dst + off) = pk.u;
}

// ============ qkv GEMM: BM=256, BN=128, BK=64, single-buffer 2-barrier ============
// Launch arithmetic fix vs r9: grid 576 = 24x8x3 at 2 blocks/CU -> 1.125 rounds
// (r9's 768 ran 1.5 rounds), and 64 MFMA per barrier-pair per wave (vs 48) ->
// +33% work per drain exposure. acc[8][4] = 128 AGPR + ~90 VGPR = ~218 <= 256
// (honest (256,2)). LDS 48KB x 2 blocks = 96KB <= 160. Same epilogues.
__global__ __launch_bounds__(256, 2) void qkv_gemm_kernel(
        const bf16* __restrict__ hsb,
        const bf16* __restrict__ wq, const bf16* __restrict__ wk, const bf16* __restrict__ wv,
        const float* __restrict__ bq, const float* __restrict__ bv,
        const float* __restrict__ cosb, const float* __restrict__ sinb,
        bf16* __restrict__ qo, bf16* __restrict__ ko, bf16* __restrict__ vto) {
    __shared__ bf16 As[256 * 64];
    __shared__ bf16 Bs[128 * 64];

    const int b    = blockIdx.x;
    const int swzi = (b & 7) * 72 + (b >> 3);     // bijective: 576 % 8 == 0
    const int bn   = swzi & 7;
    const int t1   = swzi >> 3;                   // 0..71
    const int bm   = t1 % 24;
    const int z    = t1 / 24;
    const bf16*  W    = (z == 0) ? wq : (z == 1) ? wk : wv;
    const float* bias = (z == 0) ? bq : (z == 1) ? nullptr : bv;

    const int tid  = threadIdx.x;
    const int lane = tid & 63;
    const int wid  = tid >> 6;
    const int l15  = lane & 15, l4 = lane >> 4;
    const int wr   = wid >> 1, wc = wid & 1;

    f32x4 acc[8][4] = {};

    const bf16* Ag = hsb + (size_t)bm * 256 * E_DIM;
    const bf16* Bg = W   + (size_t)bn * 128 * E_DIM;

    const int srow = tid >> 3, sc8 = (tid & 7) * 8;

    for (int k0 = 0; k0 < E_DIM; k0 += 64) {
        #pragma unroll
        for (int j = 0; j < 8; ++j)            // A: 256 rows
            gload16(Ag + (size_t)(j * 32 + srow) * E_DIM + k0 + sc8,
                    As + (size_t)(j * 256 + wid * 64) * 8);
        #pragma unroll
        for (int j = 0; j < 4; ++j)            // B: 128 rows
            gload16(Bg + (size_t)(j * 32 + srow) * E_DIM + k0 + sc8,
                    Bs + (size_t)(j * 256 + wid * 64) * 8);
        __syncthreads();

        bf16x8 bfr[4][2];
        #pragma unroll
        for (int n = 0; n < 4; ++n)
            #pragma unroll
            for (int ks = 0; ks < 2; ++ks)
                bfr[n][ks] = *reinterpret_cast<const bf16x8*>(
                    &Bs[(wc * 64 + n * 16 + l15) * 64 + (ks * 4 + l4) * 8]);
        #pragma unroll
        for (int m = 0; m < 8; ++m) {
            bf16x8 af0 = *reinterpret_cast<const bf16x8*>(
                &As[(wr * 128 + m * 16 + l15) * 64 + l4 * 8]);
            bf16x8 af1 = *reinterpret_cast<const bf16x8*>(
                &As[(wr * 128 + m * 16 + l15) * 64 + (4 + l4) * 8]);
            #pragma unroll
            for (int n = 0; n < 4; ++n) {
                acc[m][n] = __builtin_amdgcn_mfma_f32_16x16x32_bf16(af0, bfr[n][0], acc[m][n], 0, 0, 0);
                acc[m][n] = __builtin_amdgcn_mfma_f32_16x16x32_bf16(af1, bfr[n][1], acc[m][n], 0, 0, 0);
            }
        }
        __syncthreads();
    }

    const int colb = bn * 128 + wc * 64;
    if (z <= 1) {
        bf16* out = (z == 0) ? qo : ko;
        // RoPE: wave cols = one head; pair (d, d+32) = (n, n+2)
        #pragma unroll
        for (int n = 0; n < 2; ++n) {
            const int col_lo = colb + n * 16 + l15;
            const int dlo    = n * 16 + l15;
            const float b_lo = bias ? bias[col_lo] : 0.0f;
            const float b_hi = bias ? bias[col_lo + 32] : 0.0f;
            #pragma unroll
            for (int m = 0; m < 8; ++m) {
                #pragma unroll
                for (int r = 0; r < 4; ++r) {
                    const int t = bm * 256 + wr * 128 + m * 16 + l4 * 4 + r;
                    const float c = cosb[t * 64 + dlo];
                    const float s = sinb[t * 64 + dlo];
                    const float lo = acc[m][n][r] + b_lo;
                    const float hi = acc[m][n + 2][r] + b_hi;
                    out[(size_t)t * E_DIM + col_lo]      = (bf16)(lo * c - hi * s);
                    out[(size_t)t * E_DIM + col_lo + 32] = (bf16)(hi * c + lo * s);
                }
            }
        }
    } else {
        // V: write transposed vt[col][t]; 4 t-values contiguous -> 8B stores
        #pragma unroll
        for (int n = 0; n < 4; ++n) {
            const int col  = colb + n * 16 + l15;
            const float bc = bias[col];
            #pragma unroll
            for (int m = 0; m < 8; ++m) {
                const int t0r = bm * 256 + wr * 128 + m * 16 + l4 * 4;
                bf16x4 pk;
                #pragma unroll
                for (int r = 0; r < 4; ++r)
                    pk[r] = (bf16)(acc[m][n][r] + bc);
                *reinterpret_cast<bf16x4*>(vto + (size_t)col * T_TOT + t0r) = pk;
            }
        }
    }
}

// ---------------- out GEMM (r9 exact): BM=64, BN=128, BK=64 ----------------
__global__ __launch_bounds__(256, 4) void out_gemm_kernel(
        const bf16* __restrict__ attnb, const bf16* __restrict__ wo,
        const float* __restrict__ bo, float* __restrict__ out) {
    __shared__ bf16 As[64 * 64];
    __shared__ bf16 Bs[128 * 64];
    const int b   = blockIdx.x;
    const int swz = (b & 7) * 96 + (b >> 3);
    const int bn  = swz & 7;
    const int bm  = swz >> 3;

    const int tid  = threadIdx.x;
    const int lane = tid & 63;
    const int wid  = tid >> 6;
    const int l15  = lane & 15, l4 = lane >> 4;
    const int wr   = wid >> 1, wc = wid & 1;

    f32x4 acc[2][4] = {};

    const bf16* Ag = attnb + (size_t)bm * 64 * E_DIM;
    const bf16* Bg = wo    + (size_t)bn * 128 * E_DIM;

    const int srow = tid >> 3, sc8 = (tid & 7) * 8;

    for (int k0 = 0; k0 < E_DIM; k0 += 64) {
        #pragma unroll
        for (int j = 0; j < 2; ++j)
            gload16(Ag + (size_t)(j * 32 + srow) * E_DIM + k0 + sc8,
                    As + (size_t)(j * 256 + wid * 64) * 8);
        #pragma unroll
        for (int j = 0; j < 4; ++j)
            gload16(Bg + (size_t)(j * 32 + srow) * E_DIM + k0 + sc8,
                    Bs + (size_t)(j * 256 + wid * 64) * 8);
        __syncthreads();

        bf16x8 bfr[4][2];
        #pragma unroll
        for (int n = 0; n < 4; ++n)
            #pragma unroll
            for (int ks = 0; ks < 2; ++ks)
                bfr[n][ks] = *reinterpret_cast<const bf16x8*>(
                    &Bs[(wc * 64 + n * 16 + l15) * 64 + (ks * 4 + l4) * 8]);
        #pragma unroll
        for (int m = 0; m < 2; ++m) {
            bf16x8 af0 = *reinterpret_cast<const bf16x8*>(
                &As[(wr * 32 + m * 16 + l15) * 64 + l4 * 8]);
            bf16x8 af1 = *reinterpret_cast<const bf16x8*>(
                &As[(wr * 32 + m * 16 + l15) * 64 + (4 + l4) * 8]);
            #pragma unroll
            for (int n = 0; n < 4; ++n) {
                acc[m][n] = __builtin_amdgcn_mfma_f32_16x16x32_bf16(af0, bfr[n][0], acc[m][n], 0, 0, 0);
                acc[m][n] = __builtin_amdgcn_mfma_f32_16x16x32_bf16(af1, bfr[n][1], acc[m][n], 0, 0, 0);
            }
        }
        __syncthreads();
    }

    #pragma unroll
    for (int n = 0; n < 4; ++n) {
        const int col  = bn * 128 + wc * 64 + n * 16 + l15;
        const float bc = bo[col];
        #pragma unroll
        for (int m = 0; m < 2; ++m) {
            const int rowb = bm * 64 + wr * 32 + m * 16 + l4 * 4;
            #pragma unroll
            for (int r = 0; r < 4; ++r)
                out[(size_t)(rowb + r) * E_DIM + col] = acc[m][n][r] + bc;
        }
    }
}

// ---------------- flash attention: r11 body + mirrored q-tile PAIRING (r14 best) ----------------
__device__ const int g_pair_b[48] = {
    0,6,0,6,0,6,0,1,0,1,0,1,0,1,0,5,4,5,4,5,4,5,4,5,
    4,2,4,2,4,2,4,2,3,2,3,2,3,7,3,7,3,7,3,7,3,7,7,7};
__device__ const int g_pair_j[48] = {
    0,2,1,1,2,0,3,3,4,2,5,1,6,0,7,4,0,3,1,2,2,1,3,0,
    4,5,5,4,6,3,7,2,0,1,1,0,2,6,3,5,4,4,5,3,6,2,0,1};

__device__ __forceinline__ void stage_kv(const bf16* __restrict__ kp, const bf16* __restrict__ vtp,
                                         bf16* kls, bf16* vls, int tok0, int h,
                                         int wid, int lane) {
    #pragma unroll
    for (int j = 0; j < 2; ++j) {
        const int c   = j * 256 + wid * 64 + lane;
        const int row = c >> 3;
        const int c8s = (c & 7) ^ (row & 7);
        gload16(kp  + (size_t)(tok0 + row) * E_DIM + h * 64 + c8s * 8,
                kls + (size_t)(j * 256 + wid * 64) * 8);
        gload16(vtp + (size_t)(h * 64 + row) * T_TOT + tok0 + c8s * 8,
                vls + (size_t)(j * 256 + wid * 64) * 8);
    }
}

__device__ __forceinline__ int swz(int j, int col8) {
    return j * 64 + ((col8 ^ (j & 7)) << 3);
}

__global__ __launch_bounds__(256, 3) void attn_kernel(const bf16* __restrict__ q,
                                                      const bf16* __restrict__ k,
                                                      const bf16* __restrict__ vt,
                                                      bf16* __restrict__ attn) {
    const int cu[9] = {0, 1024, 1536, 2304, 3200, 4224, 4864, 5248, 6144};
    __shared__ bf16 kls[2][64 * 64];
    __shared__ bf16 vls[2][64 * 64];
    __shared__ bf16 p_lds[4][16][72];
    const int h   = blockIdx.x & 15;
    const int pid = blockIdx.x >> 4;
    const int tid = threadIdx.x, lane = tid & 63, wid = tid >> 6;
    const int l15 = lane & 15, l4 = lane >> 4;

    const int b   = g_pair_b[pid];
    const int jlo = g_pair_j[pid];
    const int nq  = (cu[b + 1] - cu[b]) >> 6;

    #pragma unroll 1
    for (int pass = 0; pass < 2; ++pass) {
        const int j   = pass ? (nq - 1 - jlo) : jlo;
        const int q0  = cu[b] + j * 64 + wid * 16;
        const int nkt = j + 1;
        const int pq  = j * 64 + wid * 16 + l15;

        bf16x8 qf[2];
        #pragma unroll
        for (int kk = 0; kk < 2; ++kk) {
            bf16x8 raw = *reinterpret_cast<const bf16x8*>(
                q + (size_t)(q0 + l15) * E_DIM + h * 64 + kk * 32 + l4 * 8);
            #pragma unroll
            for (int e = 0; e < 8; ++e)
                qf[kk][e] = (bf16)((float)raw[e] * 0.125f);
        }

        f32x4 o[4] = {};
        float mcur = -1e30f, lcur = 0.0f;

        stage_kv(k, vt, kls[0], vls[0], cu[b], h, wid, lane);
        __syncthreads();

        for (int kt = 0; kt < nkt; ++kt) {
            const int cur = kt & 1;
            if (kt + 1 < nkt)
                stage_kv(k, vt, kls[cur ^ 1], vls[cur ^ 1], cu[b] + (kt + 1) * 64, h, wid, lane);

            const int j0 = kt * 64;
            const bool diag = (kt == nkt - 1);

            f32x4 s[4] = {};
            #pragma unroll
            for (int nt = 0; nt < 4; ++nt) {
                #pragma unroll
                for (int kk = 0; kk < 2; ++kk) {
                    bf16x8 kf = *reinterpret_cast<const bf16x8*>(&kls[cur][swz(nt * 16 + l15, kk * 4 + l4)]);
                    s[nt] = __builtin_amdgcn_mfma_f32_16x16x32_bf16(kf, qf[kk], s[nt], 0, 0, 0);
                }
            }

            float tmax = -1e30f;
            #pragma unroll
            for (int nt = 0; nt < 4; ++nt) {
                #pragma unroll
                for (int r = 0; r < 4; ++r) {
                    float sv = s[nt][r];
                    if (diag) {
                        const int kp = j0 + nt * 16 + l4 * 4 + r;
                        sv = (kp <= pq) ? sv : -1e30f;
                    }
                    s[nt][r] = sv;
                    tmax = fmaxf(tmax, sv);
                }
            }
            tmax = fmaxf(tmax, __shfl_xor(tmax, 16));
            tmax = fmaxf(tmax, __shfl_xor(tmax, 32));

            if (!__all(tmax <= mcur + 8.0f)) {
                const float mnew  = fmaxf(mcur, tmax);
                const float alpha = __expf(mcur - mnew);
                #pragma unroll
                for (int nt = 0; nt < 4; ++nt)
                    #pragma unroll
                    for (int r = 0; r < 4; ++r) o[nt][r] *= alpha;
                lcur *= alpha;
                mcur = mnew;
            }

            float rs = 0.0f;
            #pragma unroll
            for (int nt = 0; nt < 4; ++nt) {
                bf16x4 pk;
                #pragma unroll
                for (int r = 0; r < 4; ++r) {
                    float p = __expf(s[nt][r] - mcur);
                    rs += p;
                    pk[r] = (bf16)p;
                }
                *reinterpret_cast<bf16x4*>(&p_lds[wid][l15][nt * 16 + l4 * 4]) = pk;
            }
            rs += __shfl_xor(rs, 16);
            rs += __shfl_xor(rs, 32);
            lcur += rs;

            bf16x8 pf[2];
            #pragma unroll
            for (int kk = 0; kk < 2; ++kk)
                pf[kk] = *reinterpret_cast<const bf16x8*>(&p_lds[wid][l15][kk * 32 + l4 * 8]);

            #pragma unroll
            for (int nt = 0; nt < 4; ++nt) {
                #pragma unroll
                for (int kk = 0; kk < 2; ++kk) {
                    bf16x8 vf = *reinterpret_cast<const bf16x8*>(&vls[cur][swz(nt * 16 + l15, kk * 4 + l4)]);
                    o[nt] = __builtin_amdgcn_mfma_f32_16x16x32_bf16(vf, pf[kk], o[nt], 0, 0, 0);
                }
            }
            __syncthreads();
        }

        const float rinv = __builtin_amdgcn_rcpf(lcur);
        #pragma unroll
        for (int nt = 0; nt < 4; ++nt) {
            bf16x4 pk;
            #pragma unroll
            for (int r = 0; r < 4; ++r)
                pk[r] = (bf16)(o[nt][r] * rinv);
            *reinterpret_cast<bf16x4*>(
                attn + (size_t)(q0 + l15) * E_DIM + h * 64 + nt * 16 + l4 * 4) = pk;
        }
    }
}

extern "C" void kernel_launch(void* const* d_in, const int* in_sizes, int n_in,
                              void* d_out, int out_size, void* d_ws, size_t ws_size,
                              hipStream_t stream) {
    const float* hs   = (const float*)d_in[0];
    const float* cosb = (const float*)d_in[2];
    const float* sinb = (const float*)d_in[3];
    const float* Wq   = (const float*)d_in[4];
    const float* bq   = (const float*)d_in[5];
    const float* Wk   = (const float*)d_in[6];
    const float* Wv   = (const float*)d_in[7];
    const float* bv   = (const float*)d_in[8];
    const float* Wo   = (const float*)d_in[9];
    const float* bo   = (const float*)d_in[10];

    const size_t TE = (size_t)T_TOT * E_DIM;
    const size_t EE = (size_t)E_DIM * E_DIM;

    char* w = (char*)d_ws;
    bf16* hsb   = (bf16*)w; w += TE * 2;
    bf16* wqb   = (bf16*)w; w += EE * 2;
    bf16* wkb   = (bf16*)w; w += EE * 2;
    bf16* wvb   = (bf16*)w; w += EE * 2;
    bf16* wob   = (bf16*)w; w += EE * 2;
    bf16* qb    = (bf16*)w; w += TE * 2;
    bf16* kb    = (bf16*)w; w += TE * 2;
    bf16* vtb   = (bf16*)w; w += TE * 2;
    bf16* attnb = (bf16*)w; w += TE * 2;

    const int cvt_blocks = (int)((TE + 4 * EE) / 4 / 256);
    cvt_all_kernel<<<cvt_blocks, 256, 0, stream>>>(hs, Wq, Wk, Wv, Wo, hsb, wqb, wkb, wvb, wob);

    // BM=256 qkv: 576 blocks at 2/CU -> 1.125 rounds (was 1.5), 64 MFMA/drain-pair
    qkv_gemm_kernel<<<576, 256, 0, stream>>>(hsb, wqb, wkb, wvb, bq, bv, cosb, sinb, qb, kb, vtb);

    attn_kernel<<<768, 256, 0, stream>>>(qb, kb, vtb, attnb);

    out_gemm_kernel<<<768, 256, 0, stream>>>(attnb, wob, bo, (float*)d_out);
}

// Round 18
// 112.954 us; speedup vs baseline: 1.2059x; 1.2059x over previous
//
#include <hip/hip_runtime.h>
#include <stdint.h>

typedef __bf16 bf16;
typedef __bf16 bf16x8 __attribute__((ext_vector_type(8)));
typedef __bf16 bf16x4 __attribute__((ext_vector_type(4)));
typedef float f32x4 __attribute__((ext_vector_type(4)));

#define T_TOT 6144
#define E_DIM 1024
#define NHEAD 16

// async global->LDS, 16B per lane; LDS dest = wave-uniform base + lane*16
__device__ __forceinline__ void gload16(const void* g, void* l) {
    __builtin_amdgcn_global_load_lds((const __attribute__((address_space(1))) void*)g,
                                     (__attribute__((address_space(3))) void*)l, 16, 0, 0);
}

// ---------------- fused f32 -> bf16 conversion (all 5 buffers) ----------------
__global__ __launch_bounds__(256) void cvt_all_kernel(const float* __restrict__ hs,
        const float* __restrict__ wq, const float* __restrict__ wk,
        const float* __restrict__ wv, const float* __restrict__ wo,
        bf16* __restrict__ hsb, bf16* __restrict__ wqb, bf16* __restrict__ wkb,
        bf16* __restrict__ wvb, bf16* __restrict__ wob) {
    const size_t TE = (size_t)T_TOT * E_DIM;
    const size_t EE = (size_t)E_DIM * E_DIM;
    size_t i = ((size_t)blockIdx.x * 256 + threadIdx.x) * 4;
    const float* src; bf16* dst; size_t off;
    if (i < TE)               { src = hs; dst = hsb; off = i; }
    else if (i < TE + EE)     { src = wq; dst = wqb; off = i - TE; }
    else if (i < TE + 2 * EE) { src = wk; dst = wkb; off = i - TE - EE; }
    else if (i < TE + 3 * EE) { src = wv; dst = wvb; off = i - TE - 2 * EE; }
    else                      { src = wo; dst = wob; off = i - TE - 3 * EE; }
    float4 v = *reinterpret_cast<const float4*>(src + off);
    union { bf16 h[4]; uint2 u; } pk;
    pk.h[0] = (bf16)v.x; pk.h[1] = (bf16)v.y; pk.h[2] = (bf16)v.z; pk.h[3] = (bf16)v.w;
    *reinterpret_cast<uint2*>(dst + off) = pk.u;
}

// ============ qkv GEMM (r9 exact — measured best of 8 variants): ============
// BM=192, BN=128, BK=64, single-buffer 2-barrier, grid 768 swizzled, (256,2).
// Structural plateau ~610 TF: dbuf/8-phase/fused-N/persistent/counted-vmcnt/
// 4-blk-CU/BM=256 all measured worse (r4,r5,r8,r10,r12,r13,r17). Do not touch.
__global__ __launch_bounds__(256, 2) void qkv_gemm_kernel(
        const bf16* __restrict__ hsb,
        const bf16* __restrict__ wq, const bf16* __restrict__ wk, const bf16* __restrict__ wv,
        const float* __restrict__ bq, const float* __restrict__ bv,
        const float* __restrict__ cosb, const float* __restrict__ sinb,
        bf16* __restrict__ qo, bf16* __restrict__ ko, bf16* __restrict__ vto) {
    __shared__ bf16 As[192 * 64];
    __shared__ bf16 Bs[128 * 64];

    const int b    = blockIdx.x;
    const int swzi = (b & 7) * 96 + (b >> 3);     // bijective: 768 % 8 == 0
    const int bn   = swzi & 7;
    const int t1   = swzi >> 3;
    const int bm   = t1 & 31;
    const int z    = t1 >> 5;
    const bf16*  W    = (z == 0) ? wq : (z == 1) ? wk : wv;
    const float* bias = (z == 0) ? bq : (z == 1) ? nullptr : bv;

    const int tid  = threadIdx.x;
    const int lane = tid & 63;
    const int wid  = tid >> 6;
    const int l15  = lane & 15, l4 = lane >> 4;
    const int wr   = wid >> 1, wc = wid & 1;

    f32x4 acc[6][4] = {};

    const bf16* Ag = hsb + (size_t)bm * 192 * E_DIM;
    const bf16* Bg = W   + (size_t)bn * 128 * E_DIM;

    const int srow = tid >> 3, sc8 = (tid & 7) * 8;

    for (int k0 = 0; k0 < E_DIM; k0 += 64) {
        #pragma unroll
        for (int j = 0; j < 6; ++j)
            gload16(Ag + (size_t)(j * 32 + srow) * E_DIM + k0 + sc8,
                    As + (size_t)(j * 256 + wid * 64) * 8);
        #pragma unroll
        for (int j = 0; j < 4; ++j)
            gload16(Bg + (size_t)(j * 32 + srow) * E_DIM + k0 + sc8,
                    Bs + (size_t)(j * 256 + wid * 64) * 8);
        __syncthreads();

        bf16x8 bfr[4][2];
        #pragma unroll
        for (int n = 0; n < 4; ++n)
            #pragma unroll
            for (int ks = 0; ks < 2; ++ks)
                bfr[n][ks] = *reinterpret_cast<const bf16x8*>(
                    &Bs[(wc * 64 + n * 16 + l15) * 64 + (ks * 4 + l4) * 8]);
        #pragma unroll
        for (int m = 0; m < 6; ++m) {
            bf16x8 af0 = *reinterpret_cast<const bf16x8*>(
                &As[(wr * 96 + m * 16 + l15) * 64 + l4 * 8]);
            bf16x8 af1 = *reinterpret_cast<const bf16x8*>(
                &As[(wr * 96 + m * 16 + l15) * 64 + (4 + l4) * 8]);
            #pragma unroll
            for (int n = 0; n < 4; ++n) {
                acc[m][n] = __builtin_amdgcn_mfma_f32_16x16x32_bf16(af0, bfr[n][0], acc[m][n], 0, 0, 0);
                acc[m][n] = __builtin_amdgcn_mfma_f32_16x16x32_bf16(af1, bfr[n][1], acc[m][n], 0, 0, 0);
            }
        }
        __syncthreads();
    }

    const int colb = bn * 128 + wc * 64;
    if (z <= 1) {
        bf16* out = (z == 0) ? qo : ko;
        // RoPE: wave cols = one head; pair (d, d+32) = (n, n+2)
        #pragma unroll
        for (int n = 0; n < 2; ++n) {
            const int col_lo = colb + n * 16 + l15;
            const int dlo    = n * 16 + l15;
            const float b_lo = bias ? bias[col_lo] : 0.0f;
            const float b_hi = bias ? bias[col_lo + 32] : 0.0f;
            #pragma unroll
            for (int m = 0; m < 6; ++m) {
                #pragma unroll
                for (int r = 0; r < 4; ++r) {
                    const int t = bm * 192 + wr * 96 + m * 16 + l4 * 4 + r;
                    const float c = cosb[t * 64 + dlo];
                    const float s = sinb[t * 64 + dlo];
                    const float lo = acc[m][n][r] + b_lo;
                    const float hi = acc[m][n + 2][r] + b_hi;
                    out[(size_t)t * E_DIM + col_lo]      = (bf16)(lo * c - hi * s);
                    out[(size_t)t * E_DIM + col_lo + 32] = (bf16)(hi * c + lo * s);
                }
            }
        }
    } else {
        // V: write transposed vt[col][t]; 4 t-values contiguous -> 8B stores
        #pragma unroll
        for (int n = 0; n < 4; ++n) {
            const int col  = colb + n * 16 + l15;
            const float bc = bias[col];
            #pragma unroll
            for (int m = 0; m < 6; ++m) {
                const int t0r = bm * 192 + wr * 96 + m * 16 + l4 * 4;
                bf16x4 pk;
                #pragma unroll
                for (int r = 0; r < 4; ++r)
                    pk[r] = (bf16)(acc[m][n][r] + bc);
                *reinterpret_cast<bf16x4*>(vto + (size_t)col * T_TOT + t0r) = pk;
            }
        }
    }
}

// ---------------- out GEMM (r9 exact): BM=64, BN=128, BK=64 ----------------
__global__ __launch_bounds__(256, 4) void out_gemm_kernel(
        const bf16* __restrict__ attnb, const bf16* __restrict__ wo,
        const float* __restrict__ bo, float* __restrict__ out) {
    __shared__ bf16 As[64 * 64];
    __shared__ bf16 Bs[128 * 64];
    const int b   = blockIdx.x;
    const int swz = (b & 7) * 96 + (b >> 3);
    const int bn  = swz & 7;
    const int bm  = swz >> 3;

    const int tid  = threadIdx.x;
    const int lane = tid & 63;
    const int wid  = tid >> 6;
    const int l15  = lane & 15, l4 = lane >> 4;
    const int wr   = wid >> 1, wc = wid & 1;

    f32x4 acc[2][4] = {};

    const bf16* Ag = attnb + (size_t)bm * 64 * E_DIM;
    const bf16* Bg = wo    + (size_t)bn * 128 * E_DIM;

    const int srow = tid >> 3, sc8 = (tid & 7) * 8;

    for (int k0 = 0; k0 < E_DIM; k0 += 64) {
        #pragma unroll
        for (int j = 0; j < 2; ++j)
            gload16(Ag + (size_t)(j * 32 + srow) * E_DIM + k0 + sc8,
                    As + (size_t)(j * 256 + wid * 64) * 8);
        #pragma unroll
        for (int j = 0; j < 4; ++j)
            gload16(Bg + (size_t)(j * 32 + srow) * E_DIM + k0 + sc8,
                    Bs + (size_t)(j * 256 + wid * 64) * 8);
        __syncthreads();

        bf16x8 bfr[4][2];
        #pragma unroll
        for (int n = 0; n < 4; ++n)
            #pragma unroll
            for (int ks = 0; ks < 2; ++ks)
                bfr[n][ks] = *reinterpret_cast<const bf16x8*>(
                    &Bs[(wc * 64 + n * 16 + l15) * 64 + (ks * 4 + l4) * 8]);
        #pragma unroll
        for (int m = 0; m < 2; ++m) {
            bf16x8 af0 = *reinterpret_cast<const bf16x8*>(
                &As[(wr * 32 + m * 16 + l15) * 64 + l4 * 8]);
            bf16x8 af1 = *reinterpret_cast<const bf16x8*>(
                &As[(wr * 32 + m * 16 + l15) * 64 + (4 + l4) * 8]);
            #pragma unroll
            for (int n = 0; n < 4; ++n) {
                acc[m][n] = __builtin_amdgcn_mfma_f32_16x16x32_bf16(af0, bfr[n][0], acc[m][n], 0, 0, 0);
                acc[m][n] = __builtin_amdgcn_mfma_f32_16x16x32_bf16(af1, bfr[n][1], acc[m][n], 0, 0, 0);
            }
        }
        __syncthreads();
    }

    #pragma unroll
    for (int n = 0; n < 4; ++n) {
        const int col  = bn * 128 + wc * 64 + n * 16 + l15;
        const float bc = bo[col];
        #pragma unroll
        for (int m = 0; m < 2; ++m) {
            const int rowb = bm * 64 + wr * 32 + m * 16 + l4 * 4;
            #pragma unroll
            for (int r = 0; r < 4; ++r)
                out[(size_t)(rowb + r) * E_DIM + col] = acc[m][n][r] + bc;
        }
    }
}

// ---------------- flash attention: r11 body + mirrored q-tile PAIRING (r14 best) ----------------
// Pair q-tile j with (nq-1-j) of the same sequence as two sequential passes:
// per-block work = nq+1 tiles, constant within a sequence. Grid 48 pairs x 16
// heads = 768 blocks = exactly 3/CU. Joint-fusion of the two passes (r15) and
// BM growth (r17) both measured worse.
__device__ const int g_pair_b[48] = {
    0,6,0,6,0,6,0,1,0,1,0,1,0,1,0,5,4,5,4,5,4,5,4,5,
    4,2,4,2,4,2,4,2,3,2,3,2,3,7,3,7,3,7,3,7,3,7,7,7};
__device__ const int g_pair_j[48] = {
    0,2,1,1,2,0,3,3,4,2,5,1,6,0,7,4,0,3,1,2,2,1,3,0,
    4,5,5,4,6,3,7,2,0,1,1,0,2,6,3,5,4,4,5,3,6,2,0,1};

__device__ __forceinline__ void stage_kv(const bf16* __restrict__ kp, const bf16* __restrict__ vtp,
                                         bf16* kls, bf16* vls, int tok0, int h,
                                         int wid, int lane) {
    #pragma unroll
    for (int j = 0; j < 2; ++j) {
        const int c   = j * 256 + wid * 64 + lane;
        const int row = c >> 3;
        const int c8s = (c & 7) ^ (row & 7);
        gload16(kp  + (size_t)(tok0 + row) * E_DIM + h * 64 + c8s * 8,
                kls + (size_t)(j * 256 + wid * 64) * 8);
        gload16(vtp + (size_t)(h * 64 + row) * T_TOT + tok0 + c8s * 8,
                vls + (size_t)(j * 256 + wid * 64) * 8);
    }
}

__device__ __forceinline__ int swz(int j, int col8) {
    return j * 64 + ((col8 ^ (j & 7)) << 3);
}

__global__ __launch_bounds__(256, 3) void attn_kernel(const bf16* __restrict__ q,
                                                      const bf16* __restrict__ k,
                                                      const bf16* __restrict__ vt,
                                                      bf16* __restrict__ attn) {
    const int cu[9] = {0, 1024, 1536, 2304, 3200, 4224, 4864, 5248, 6144};
    __shared__ bf16 kls[2][64 * 64];
    __shared__ bf16 vls[2][64 * 64];
    __shared__ bf16 p_lds[4][16][72];
    const int h   = blockIdx.x & 15;
    const int pid = blockIdx.x >> 4;
    const int tid = threadIdx.x, lane = tid & 63, wid = tid >> 6;
    const int l15 = lane & 15, l4 = lane >> 4;

    const int b   = g_pair_b[pid];
    const int jlo = g_pair_j[pid];
    const int nq  = (cu[b + 1] - cu[b]) >> 6;

    #pragma unroll 1
    for (int pass = 0; pass < 2; ++pass) {
        const int j   = pass ? (nq - 1 - jlo) : jlo;
        const int q0  = cu[b] + j * 64 + wid * 16;   // wave's first global token
        const int nkt = j + 1;
        const int pq  = j * 64 + wid * 16 + l15;     // lane's q local position

        // Q fragments with 0.125 folded in (exact bf16 scaling: power of 2)
        bf16x8 qf[2];
        #pragma unroll
        for (int kk = 0; kk < 2; ++kk) {
            bf16x8 raw = *reinterpret_cast<const bf16x8*>(
                q + (size_t)(q0 + l15) * E_DIM + h * 64 + kk * 32 + l4 * 8);
            #pragma unroll
            for (int e = 0; e < 8; ++e)
                qf[kk][e] = (bf16)((float)raw[e] * 0.125f);
        }

        f32x4 o[4] = {};
        float mcur = -1e30f, lcur = 0.0f;   // per-lane state for q-row = l15

        stage_kv(k, vt, kls[0], vls[0], cu[b], h, wid, lane);
        __syncthreads();

        for (int kt = 0; kt < nkt; ++kt) {
            const int cur = kt & 1;
            if (kt + 1 < nkt)
                stage_kv(k, vt, kls[cur ^ 1], vls[cur ^ 1], cu[b] + (kt + 1) * 64, h, wid, lane);

            const int j0 = kt * 64;
            const bool diag = (kt == nkt - 1);

            // S^T = K Q^T (pre-scaled): lane holds q = l15, k = j0 + nt*16 + l4*4 + r
            f32x4 s[4] = {};
            #pragma unroll
            for (int nt = 0; nt < 4; ++nt) {
                #pragma unroll
                for (int kk = 0; kk < 2; ++kk) {
                    bf16x8 kf = *reinterpret_cast<const bf16x8*>(&kls[cur][swz(nt * 16 + l15, kk * 4 + l4)]);
                    s[nt] = __builtin_amdgcn_mfma_f32_16x16x32_bf16(kf, qf[kk], s[nt], 0, 0, 0);
                }
            }

            float tmax = -1e30f;
            #pragma unroll
            for (int nt = 0; nt < 4; ++nt) {
                #pragma unroll
                for (int r = 0; r < 4; ++r) {
                    float sv = s[nt][r];
                    if (diag) {
                        const int kp = j0 + nt * 16 + l4 * 4 + r;
                        sv = (kp <= pq) ? sv : -1e30f;
                    }
                    s[nt][r] = sv;
                    tmax = fmaxf(tmax, sv);
                }
            }
            tmax = fmaxf(tmax, __shfl_xor(tmax, 16));
            tmax = fmaxf(tmax, __shfl_xor(tmax, 32));

            // defer-max (T13): only rescale when some lane's max grew past m+8
            if (!__all(tmax <= mcur + 8.0f)) {
                const float mnew  = fmaxf(mcur, tmax);
                const float alpha = __expf(mcur - mnew);
                #pragma unroll
                for (int nt = 0; nt < 4; ++nt)
                    #pragma unroll
                    for (int r = 0; r < 4; ++r) o[nt][r] *= alpha;
                lcur *= alpha;
                mcur = mnew;
            }

            float rs = 0.0f;
            #pragma unroll
            for (int nt = 0; nt < 4; ++nt) {
                bf16x4 pk;
                #pragma unroll
                for (int r = 0; r < 4; ++r) {
                    float p = __expf(s[nt][r] - mcur);
                    rs += p;
                    pk[r] = (bf16)p;
                }
                *reinterpret_cast<bf16x4*>(&p_lds[wid][l15][nt * 16 + l4 * 4]) = pk;
            }
            rs += __shfl_xor(rs, 16);
            rs += __shfl_xor(rs, 32);
            lcur += rs;

            // P^T fragments (B-operand of swapped PV)
            bf16x8 pf[2];
            #pragma unroll
            for (int kk = 0; kk < 2; ++kk)
                pf[kk] = *reinterpret_cast<const bf16x8*>(&p_lds[wid][l15][kk * 32 + l4 * 8]);

            // O^T += V^T P^T : D col = q = l15 (lane-local softmax state)
            #pragma unroll
            for (int nt = 0; nt < 4; ++nt) {
                #pragma unroll
                for (int kk = 0; kk < 2; ++kk) {
                    bf16x8 vf = *reinterpret_cast<const bf16x8*>(&vls[cur][swz(nt * 16 + l15, kk * 4 + l4)]);
                    o[nt] = __builtin_amdgcn_mfma_f32_16x16x32_bf16(vf, pf[kk], o[nt], 0, 0, 0);
                }
            }
            __syncthreads();
        }

        // epilogue: lane-local normalize; o[nt][r] = O[q=l15][d = nt*16 + l4*4 + r]
        const float rinv = __builtin_amdgcn_rcpf(lcur);
        #pragma unroll
        for (int nt = 0; nt < 4; ++nt) {
            bf16x4 pk;
            #pragma unroll
            for (int r = 0; r < 4; ++r)
                pk[r] = (bf16)(o[nt][r] * rinv);
            *reinterpret_cast<bf16x4*>(
                attn + (size_t)(q0 + l15) * E_DIM + h * 64 + nt * 16 + l4 * 4) = pk;
        }
    }
}

extern "C" void kernel_launch(void* const* d_in, const int* in_sizes, int n_in,
                              void* d_out, int out_size, void* d_ws, size_t ws_size,
                              hipStream_t stream) {
    const float* hs   = (const float*)d_in[0];
    const float* cosb = (const float*)d_in[2];
    const float* sinb = (const float*)d_in[3];
    const float* Wq   = (const float*)d_in[4];
    const float* bq   = (const float*)d_in[5];
    const float* Wk   = (const float*)d_in[6];
    const float* Wv   = (const float*)d_in[7];
    const float* bv   = (const float*)d_in[8];
    const float* Wo   = (const float*)d_in[9];
    const float* bo   = (const float*)d_in[10];

    const size_t TE = (size_t)T_TOT * E_DIM;
    const size_t EE = (size_t)E_DIM * E_DIM;

    char* w = (char*)d_ws;
    bf16* hsb   = (bf16*)w; w += TE * 2;
    bf16* wqb   = (bf16*)w; w += EE * 2;
    bf16* wkb   = (bf16*)w; w += EE * 2;
    bf16* wvb   = (bf16*)w; w += EE * 2;
    bf16* wob   = (bf16*)w; w += EE * 2;
    bf16* qb    = (bf16*)w; w += TE * 2;
    bf16* kb    = (bf16*)w; w += TE * 2;
    bf16* vtb   = (bf16*)w; w += TE * 2;
    bf16* attnb = (bf16*)w; w += TE * 2;

    const int cvt_blocks = (int)((TE + 4 * EE) / 4 / 256);
    cvt_all_kernel<<<cvt_blocks, 256, 0, stream>>>(hs, Wq, Wk, Wv, Wo, hsb, wqb, wkb, wvb, wob);

    qkv_gemm_kernel<<<768, 256, 0, stream>>>(hsb, wqb, wkb, wvb, bq, bv, cosb, sinb, qb, kb, vtb);

    // paired q-tiles: 48 pairs x 16 heads = 768 blocks = exactly 3/CU, one round
    attn_kernel<<<768, 256, 0, stream>>>(qb, kb, vtb, attnb);

    out_gemm_kernel<<<768, 256, 0, stream>>>(attnb, wob, bo, (float*)d_out);
}